// Round 6
// baseline (486.748 us; speedup 1.0000x reference)
//
#include <hip/hip_runtime.h>
#include <stdint.h>

typedef uint32_t u32;
typedef __attribute__((ext_vector_type(8))) short bf16x8;   // 8 bf16 = 4 VGPRs
typedef __attribute__((ext_vector_type(4))) float f32x4;    // MFMA 16x16 acc

// v_dot4_i32_i8 (measured ~7 cyc/issue on gfx950 -- conv2/fc still use it)
#if defined(__has_builtin) && __has_builtin(__builtin_amdgcn_sdot4)
#define SDOT4(a,b,c) __builtin_amdgcn_sdot4((int)(a),(int)(b),(c),false)
#else
__device__ __forceinline__ int sdot4_sw(u32 a, u32 b, int c) {
    c += (int)(int8_t)(a)       * (int)(int8_t)(b);
    c += (int)(int8_t)(a >> 8)  * (int)(int8_t)(b >> 8);
    c += (int)(int8_t)(a >> 16) * (int)(int8_t)(b >> 16);
    c += (int)(int8_t)(a >> 24) * (int)(int8_t)(b >> 24);
    return c;
}
#define SDOT4(a,b,c) sdot4_sw((a),(b),(c))
#endif

__device__ __forceinline__ u32 alignb(u32 hi, u32 lo, unsigned s) {
    return (u32)((((uint64_t)hi << 32) | lo) >> (8u * s));
}
__device__ __forceinline__ u32 sgnb(float v) { return (v >= 0.f) ? 0x01u : 0xFFu; }

// quant code as exact bf16 bits (values in {-2,-1,0,1}: mantissa-exact)
__device__ __forceinline__ u32 qbf(float v, float s) {
    const float r = fminf(fmaxf(rintf(__fdiv_rn(v, s)), -2.f), 1.f);
    return __float_as_uint(r) >> 16;
}

// ---------------------------------------------------------------------------
// Prep: binarize+pack all weights once.
// w1pb: conv1 MFMA B-fragments (bf16 +-1.0 / 0), 1280 words.
//   Per ky (0..4), per lane l (0..63): 4 words = 8 bf16 = B[k=(l>>4)*8+j][c=l&15]
//   where k maps (dx=k>>2, ch=k&3); zero for c>=6, ch==3, k>=20. Zeros kill
//   every pad/garbage A-slot (0.0 * x == 0 needs x finite -> row pads zeroed
//   in k_conv1).
// w2p: [16][6][5] rows -> 2 words (planar, unchanged)            (960 words)
// fw1p: 100x400 bytes -> 10000 words ; fw2p: 50x100 -> 1250 words
// fw3p: rows padded K 50->52 -> 10x13 words
// ---------------------------------------------------------------------------
__global__ __launch_bounds__(256) void k_prep(
    const float* __restrict__ w1, const float* __restrict__ w2,
    const float* __restrict__ fw1, const float* __restrict__ fw2,
    const float* __restrict__ fw3,
    u32* __restrict__ w1pb, u32* __restrict__ w2p, u32* __restrict__ fw1p,
    u32* __restrict__ fw2p, u32* __restrict__ fw3p)
{
    const int tid = threadIdx.x;
    for (int i = tid; i < 1280; i += 256) {      // i = ((ky*64)+l)*4 + w
        const int w = i & 3, l = (i >> 2) & 63, ky = i >> 8;
        const int kg = l >> 4, cc = l & 15;
        u32 v = 0;
        #pragma unroll
        for (int h = 0; h < 2; ++h) {
            const int k = kg * 8 + w * 2 + h;    // K index 0..31
            const int ch = k & 3, dx = k >> 2;
            if (cc < 6 && dx < 5 && ch < 3) {
                const u32 s = (w1[cc*75 + ch*25 + ky*5 + dx] >= 0.f) ? 0x3F80u
                                                                     : 0xBF80u;
                v |= s << (16 * h);
            }
        }
        w1pb[i] = v;
    }
    for (int i = tid; i < 480; i += 256) {
        const float* r = w2 + i * 5;
        w2p[i*2]   = sgnb(r[0]) | (sgnb(r[1])<<8) | (sgnb(r[2])<<16) | (sgnb(r[3])<<24);
        w2p[i*2+1] = sgnb(r[4]);
    }
    for (int i = tid; i < 10000; i += 256) {
        const float* r = fw1 + i * 4;   // flat: rows are 100 words contiguous
        fw1p[i] = sgnb(r[0]) | (sgnb(r[1])<<8) | (sgnb(r[2])<<16) | (sgnb(r[3])<<24);
    }
    for (int i = tid; i < 1250; i += 256) {
        const float* r = fw2 + i * 4;
        fw2p[i] = sgnb(r[0]) | (sgnb(r[1])<<8) | (sgnb(r[2])<<16) | (sgnb(r[3])<<24);
    }
    for (int i = tid; i < 130; i += 256) {
        const int o = i / 13, j = i % 13;
        u32 v = 0;
        #pragma unroll
        for (int m = 0; m < 4; ++m) {
            const int k = 4*j + m;
            if (k < 50) v |= sgnb(fw3[o*50 + k]) << (8*m);
        }
        fw3p[i] = v;
    }
}

// ---------------------------------------------------------------------------
// Conv1 via MFMA bf16 16x16x32 (v_dot4 measured ~7cyc -> vector path is
// issue-bound; matrix pipe was idle).
// LDS codes: bf16, 4 elems/px (3ch + 0 pad) = 8 B/px; row = 32 px = 256 B
// + 32 B zero pad = 288 B stride (pads zeroed: 0-weight * garbage must not
// be NaN). One wave-task = (sample, pooled row pyr, x-half xh):
//   A: M=16 conv-x positions (x = (lane&15) + 12*xh), K=32 = one filter row
//      (5px x 4ch, upper K zero-weighted); lane reads 16 contiguous bytes at
//      row(2pyr+ky[+1])*288 + x*8 + (lane>>4)*16  (8B aligned -> 2x b64).
//   B: per-lane fragment from w1pb (col = lane&15 = channel).
//   10 MFMA per task (5 ky x 2 conv rows), acc f32 exact.
// D layout [HW-verified m89]: col=lane&15=channel, row=(lane>>4)*4+reg =
// 4 consecutive x -> maxpool pairs are IN-LANE: max(r0,r1),(r2,r3) across
// the two row-accs -> 2 pooled cols pc = 6*xh+2*kg (+1). xh=1,kg=0 skipped
// (duplicate of xh=0,kg=3). Epilogue BN/quant identical arithmetic ->
// byte-writes into stg; a1 format unchanged (conv2/fc untouched).
// ---------------------------------------------------------------------------
#define NS1 3
__global__ __launch_bounds__(256) void k_conv1(
    const float* __restrict__ x, const u32* __restrict__ w1pb,
    const float* __restrict__ b1, const float* __restrict__ bn1s,
    const float* __restrict__ bn1b, const float* __restrict__ p_sin,
    const float* __restrict__ p_sw1, const float* __restrict__ p_sa1,
    uint8_t* __restrict__ a1, int B)
{
    __shared__ __align__(16) u32 q[NS1 * 2304];   // [sl][row32][72w: 64 data+8 pad]
    __shared__ __align__(16) u32 stg[NS1 * 336];  // a1 tile, global layout
    __shared__ float cb[6], cs[6], cbb[6];
    const int tid = threadIdx.x;
    const long long b0 = (long long)blockIdx.x * NS1;

    const float s_in = p_sin[0], s_a1 = p_sa1[0];
    const float c1 = __fmul_rn(s_in, p_sw1[0]);

    if (tid < 6) { cb[tid] = b1[tid]; cs[tid] = bn1s[tid]; cbb[tid] = bn1b[tid]; }

    // B fragments: per-lane 16 B from global (5 KB total, L2-resident)
    const int lane = tid & 63;
    bf16x8 wf[5];
    #pragma unroll
    for (int ky = 0; ky < 5; ++ky) {
        const uint4 u = *(const uint4*)(w1pb + (ky * 64 + lane) * 4);
        wf[ky] = __builtin_bit_cast(bf16x8, u);
    }

    // zero stg (byte-writes only cover pc 0..13) and row pads (words 64..71)
    for (int i = tid; i < NS1 * 336; i += 256) stg[i] = 0;
    for (int i = tid; i < NS1 * 256; i += 256) {
        const int sl = i >> 8, r2 = i & 255, row = r2 >> 3, j = r2 & 7;
        q[sl * 2304 + row * 72 + 64 + j] = 0;
    }

    // stage: quantize -> bf16 codes, 4 px (x 3ch) per iteration
    for (int i = tid; i < NS1 * 256; i += 256) {
        const int sl = i >> 8, r2 = i & 255, row = r2 >> 3, xq = r2 & 7;
        if (b0 + sl < B) {
            const float* px = x + (b0 + sl) * 3072 + row * 32 + xq * 4;
            const float4 f0 = *(const float4*)(px);
            const float4 f1 = *(const float4*)(px + 1024);
            const float4 f2 = *(const float4*)(px + 2048);
            const u32 w0 = qbf(f0.x, s_in) | (qbf(f1.x, s_in) << 16);
            const u32 w1_ = qbf(f2.x, s_in);
            const u32 w2_ = qbf(f0.y, s_in) | (qbf(f1.y, s_in) << 16);
            const u32 w3_ = qbf(f2.y, s_in);
            const u32 w4_ = qbf(f0.z, s_in) | (qbf(f1.z, s_in) << 16);
            const u32 w5_ = qbf(f2.z, s_in);
            const u32 w6_ = qbf(f0.w, s_in) | (qbf(f1.w, s_in) << 16);
            const u32 w7_ = qbf(f2.w, s_in);
            u32* qp = q + sl * 2304 + row * 72 + xq * 8;
            *(uint4*)(qp)     = make_uint4(w0, w1_, w2_, w3_);
            *(uint4*)(qp + 4) = make_uint4(w4_, w5_, w6_, w7_);
        }
    }
    __syncthreads();

    const int wid = tid >> 6;
    const int kg = lane >> 4, c = lane & 15;
    const uint8_t* qbyte = (const uint8_t*)q;
    for (int t = wid; t < NS1 * 28; t += 4) {            // wave-uniform tasks
        const int sl = t / 28, rem = t % 28, pyr = rem >> 1, xh = rem & 1;
        if (b0 + sl >= B) continue;
        const int xm = (lane & 15) + 12 * xh;            // A row = conv x pos
        const uint8_t* ab = qbyte + (size_t)(sl * 32 + 2 * pyr) * 288
                          + xm * 8 + kg * 16;
        f32x4 acc0 = {0.f, 0.f, 0.f, 0.f}, acc1 = {0.f, 0.f, 0.f, 0.f};
        #pragma unroll
        for (int ky = 0; ky < 5; ++ky) {
            const uint8_t* p0 = ab + ky * 288;           // conv row 2pyr + ky
            uint2 lo = *(const uint2*)(p0);
            uint2 hi = *(const uint2*)(p0 + 8);
            acc0 = __builtin_amdgcn_mfma_f32_16x16x32_bf16(
                __builtin_bit_cast(bf16x8, make_uint4(lo.x, lo.y, hi.x, hi.y)),
                wf[ky], acc0, 0, 0, 0);
            const uint8_t* p1 = p0 + 288;                // conv row 2pyr+1 + ky
            lo = *(const uint2*)(p1);
            hi = *(const uint2*)(p1 + 8);
            acc1 = __builtin_amdgcn_mfma_f32_16x16x32_bf16(
                __builtin_bit_cast(bf16x8, make_uint4(lo.x, lo.y, hi.x, hi.y)),
                wf[ky], acc1, 0, 0, 0);
        }
        if (c < 6 && (xh == 0 || kg > 0)) {
            const float m0 = fmaxf(fmaxf(acc0[0], acc0[1]), fmaxf(acc1[0], acc1[1]));
            const float m1 = fmaxf(fmaxf(acc0[2], acc0[3]), fmaxf(acc1[2], acc1[3]));
            const float y0 = __fadd_rn(__fmul_rn(m0, c1), cb[c]);
            const float z0 = __fadd_rn(__fmul_rn(y0, cs[c]), cbb[c]);
            const float t0 = __fdiv_rn(fmaxf(z0, 0.f), s_a1);
            const float y1 = __fadd_rn(__fmul_rn(m1, c1), cb[c]);
            const float z1 = __fadd_rn(__fmul_rn(y1, cs[c]), cbb[c]);
            const float t1 = __fdiv_rn(fmaxf(z1, 0.f), s_a1);
            const int pc = 6 * xh + 2 * kg;              // pooled col of pair 1
            uint8_t* sp = (uint8_t*)stg + ((sl * 6 + c) * 14 + pyr) * 16;
            sp[pc]     = (uint8_t)(int)fminf(fmaxf(rintf(t0), 0.f), 3.f);
            sp[pc + 1] = (uint8_t)(int)fminf(fmaxf(rintf(t1), 0.f), 3.f);
        }
    }
    __syncthreads();

    const long long nv = ((long long)B - b0) * 84;   // valid uint4 rows
    if (tid < NS1 * 84 && tid < nv)
        *(uint4*)(a1 + ((size_t)b0 * 84 + tid) * 16) = ((const uint4*)stg)[tid];
}

// ---------------------------------------------------------------------------
// Conv2: conv(5x5,6->16) on a1 codes -> maxpool2 -> BN -> relu-quant2b
// Thread = (sample, c_out, pooled_row). a2 out: [B][400] plain bytes.
// ---------------------------------------------------------------------------
#define NS2 3
__global__ __launch_bounds__(256, 3) void k_conv2(
    const uint8_t* __restrict__ a1, const u32* __restrict__ w2p,
    const float* __restrict__ b2, const float* __restrict__ bn2s,
    const float* __restrict__ bn2b, const float* __restrict__ p_sa1,
    const float* __restrict__ p_sw2, const float* __restrict__ p_sa2,
    uint8_t* __restrict__ a2, int B)
{
    __shared__ u32 aL[NS2*336];         // [sl][ci6][row14][4 words]
    __shared__ u32 wp[960];
    __shared__ float cb[16], cs[16], cbb[16];
    const int tid = threadIdx.x;
    const long long b0 = (long long)blockIdx.x * NS2;

    const float c2 = __fmul_rn(p_sa1[0], p_sw2[0]);
    const float s_a2 = p_sa2[0];

    for (int i = tid; i < 960; i += 256) wp[i] = w2p[i];
    if (tid < 16) { cb[tid] = b2[tid]; cs[tid] = bn2s[tid]; cbb[tid] = bn2b[tid]; }

    const u32* a1w = (const u32*)a1;
    const long long wbase = b0 * 336;
    for (int i = tid; i < NS2*336; i += 256)
        if (wbase + i < (long long)B * 336) aL[i] = a1w[wbase + i];
    __syncthreads();

    if (tid < NS2*80) {
        const int sl = tid / 80, o = tid % 80, c = o / 5, py = o % 5;
        const long long b = b0 + sl;
        if (b < B) {
            int acc0[10], acc1[10];
            #pragma unroll
            for (int p = 0; p < 10; ++p) { acc0[p] = 0; acc1[p] = 0; }
            #pragma unroll
            for (int ci = 0; ci < 6; ++ci) {
                const u32* base = &aL[sl*336 + ci*56];
                const u32* wrow = &wp[(c*6 + ci) * 10];
                #pragma unroll
                for (int ir = 0; ir < 6; ++ir) {
                    const uint4 Wv = *(const uint4*)(base + (2*py + ir) * 4);
                    u32 W5[5] = {Wv.x, Wv.y, Wv.z, Wv.w, 0};
                    u32 e[14];
                    #pragma unroll
                    for (int j = 0; j < 4; ++j) {
                        e[4*j] = W5[j];
                        if (4*j+1 < 14) e[4*j+1] = alignb(W5[j+1], W5[j], 1);
                        if (4*j+2 < 14) e[4*j+2] = alignb(W5[j+1], W5[j], 2);
                        if (4*j+3 < 14) e[4*j+3] = alignb(W5[j+1], W5[j], 3);
                    }
                    if (ir <= 4) {
                        const u32 wa = wrow[ir*2], wb = wrow[ir*2+1];
                        #pragma unroll
                        for (int p = 0; p < 10; ++p)
                            acc0[p] = SDOT4(wa, e[p], SDOT4(wb, e[p+4], acc0[p]));
                    }
                    if (ir >= 1) {
                        const u32 wa = wrow[(ir-1)*2], wb = wrow[(ir-1)*2+1];
                        #pragma unroll
                        for (int p = 0; p < 10; ++p)
                            acc1[p] = SDOT4(wa, e[p], SDOT4(wb, e[p+4], acc1[p]));
                    }
                }
            }
            uint8_t* op = a2 + (size_t)b * 400 + c * 25 + py * 5;
            #pragma unroll
            for (int k = 0; k < 5; ++k) {
                const int m = max(max(acc0[2*k], acc0[2*k+1]),
                                  max(acc1[2*k], acc1[2*k+1]));
                const float y = __fadd_rn(__fmul_rn((float)m, c2), cb[c]);
                const float z = __fadd_rn(__fmul_rn(y, cs[c]), cbb[c]);
                const float t = __fdiv_rn(fmaxf(z, 0.f), s_a2);
                op[k] = (uint8_t)(int)fminf(fmaxf(rintf(t), 0.f), 3.f);
            }
        }
    }
}

// ---------------------------------------------------------------------------
// FC: fc1(100x400)+q -> fc2(50x100)+q -> fc3(10x50)+bias. 16 samples/block,
// packed-byte codes, sdot4 inner loops, weights staged once into LDS.
// ---------------------------------------------------------------------------
__global__ __launch_bounds__(256) void k_fc(
    const uint8_t* __restrict__ a2,
    const u32* __restrict__ fw1p, const float* __restrict__ fb1,
    const u32* __restrict__ fw2p, const float* __restrict__ fb2,
    const u32* __restrict__ fw3p, const float* __restrict__ fb3,
    const float* __restrict__ p_sa2, const float* __restrict__ p_sfw1,
    const float* __restrict__ p_sfw2, const float* __restrict__ p_sfw3,
    const float* __restrict__ p_sa3, const float* __restrict__ p_sa4,
    float* __restrict__ out, int B)
{
    __shared__ u32 w1L[10000];
    __shared__ u32 w2L[1250];
    __shared__ u32 w3L[130];
    __shared__ float bb1[100], bb2[52], bb3[12];
    __shared__ u32 xw[16*100];
    __shared__ u32 h1w[16*25];          // 100 bytes / sample
    __shared__ u32 h2w[16*13];          // 52 bytes / sample (pad = 0)
    const int tid = threadIdx.x;
    const long long b0 = (long long)blockIdx.x * 16;

    for (int i = tid; i < 10000; i += 256) w1L[i] = fw1p[i];
    for (int i = tid; i < 1250; i += 256) w2L[i] = fw2p[i];
    if (tid < 130) w3L[tid] = fw3p[tid];
    if (tid < 100) bb1[tid] = fb1[tid];
    else if (tid >= 128 && tid < 178) bb2[tid-128] = fb2[tid-128];
    else if (tid >= 192 && tid < 202) bb3[tid-192] = fb3[tid-192];
    else if (tid >= 224 && tid < 240) h2w[(tid-224)*13 + 12] = 0;
    const u32* a2w = (const u32*)a2;
    const long long wbase = b0 * 100;
    for (int i = tid; i < 1600; i += 256)
        if (wbase + i < (long long)B * 100) xw[i] = a2w[wbase + i];

    const float c3 = __fmul_rn(p_sa2[0], p_sfw1[0]);
    const float c4 = __fmul_rn(p_sa3[0], p_sfw2[0]);
    const float c5 = __fmul_rn(p_sa4[0], p_sfw3[0]);
    const float s_a3 = p_sa3[0], s_a4 = p_sa4[0];
    __syncthreads();

    for (int t = tid; t < 1600; t += 256) {
        const int s = t & 15, o = t >> 4;
        int T = 0;
        const u32* wr = &w1L[o*100];
        const u32* xr = &xw[s*100];
        #pragma unroll 10
        for (int j = 0; j < 100; ++j) T = SDOT4(wr[j], xr[j], T);
        const float y  = __fadd_rn(__fmul_rn((float)T, c3), bb1[o]);
        const float t2 = __fdiv_rn(fmaxf(y, 0.f), s_a3);
        ((uint8_t*)h1w)[s*100 + o] = (uint8_t)(int)fminf(fmaxf(rintf(t2), 0.f), 3.f);
    }
    __syncthreads();

    for (int t = tid; t < 800; t += 256) {
        const int s = t & 15, o = t >> 4;
        int T = 0;
        const u32* wr = &w2L[o*25];
        const u32* xr = &h1w[s*25];
        #pragma unroll
        for (int j = 0; j < 25; ++j) T = SDOT4(wr[j], xr[j], T);
        const float y  = __fadd_rn(__fmul_rn((float)T, c4), bb2[o]);
        const float t2 = __fdiv_rn(fmaxf(y, 0.f), s_a4);
        ((uint8_t*)h2w)[s*52 + o] = (uint8_t)(int)fminf(fmaxf(rintf(t2), 0.f), 3.f);
    }
    __syncthreads();

    for (int t = tid; t < 160; t += 256) {
        const int s = t & 15, o = t >> 4;
        if (b0 + s < B) {
            int T = 0;
            const u32* wr = &w3L[o*13];
            const u32* xr = &h2w[s*13];
            #pragma unroll
            for (int j = 0; j < 13; ++j) T = SDOT4(wr[j], xr[j], T);
            out[(size_t)(b0 + s)*10 + o] = __fadd_rn(__fmul_rn((float)T, c5), bb3[o]);
        }
    }
}

// ---------------------------------------------------------------------------
extern "C" void kernel_launch(void* const* d_in, const int* in_sizes, int n_in,
                              void* d_out, int out_size, void* d_ws, size_t ws_size,
                              hipStream_t stream)
{
    const float* x    = (const float*)d_in[0];
    const float* w1   = (const float*)d_in[1];
    const float* b1   = (const float*)d_in[2];
    const float* w2   = (const float*)d_in[3];
    const float* b2   = (const float*)d_in[4];
    const float* fw1  = (const float*)d_in[5];
    const float* fb1  = (const float*)d_in[6];
    const float* fw2  = (const float*)d_in[7];
    const float* fb2  = (const float*)d_in[8];
    const float* fw3  = (const float*)d_in[9];
    const float* fb3  = (const float*)d_in[10];
    const float* bn1s = (const float*)d_in[11];
    const float* bn1b = (const float*)d_in[12];
    const float* bn2s = (const float*)d_in[13];
    const float* bn2b = (const float*)d_in[14];
    const float* s_in = (const float*)d_in[15];
    const float* s_w1 = (const float*)d_in[16];
    const float* s_w2 = (const float*)d_in[17];
    const float* s_fw1= (const float*)d_in[18];
    const float* s_fw2= (const float*)d_in[19];
    const float* s_fw3= (const float*)d_in[20];
    const float* s_a1 = (const float*)d_in[21];
    const float* s_a2 = (const float*)d_in[22];
    const float* s_a3 = (const float*)d_in[23];
    const float* s_a4 = (const float*)d_in[24];

    int B = out_size / 10;
    if (B <= 0) B = 16384;

    // workspace carve (all 16B aligned)
    uint8_t* ws  = (uint8_t*)d_ws;
    uint8_t* a1  = ws;                                   // B*1344
    uint8_t* a2  = a1 + (size_t)B * 1344;                // B*400
    uint8_t* p   = a2 + (size_t)B * 400;
    u32* w1pb = (u32*)p;            p += 1280 * 4;       // 5120 (MFMA B-frags)
    u32* w2p  = (u32*)p;            p += 960 * 4;        // 3840
    u32* fw1p = (u32*)p;            p += 10000 * 4;      // 40000
    u32* fw2p = (u32*)p;            p += 1250 * 4 + 8;   // 5008 (keep 16B align)
    u32* fw3p = (u32*)p;

    k_prep<<<1, 256, 0, stream>>>(w1, w2, fw1, fw2, fw3,
                                  w1pb, w2p, fw1p, fw2p, fw3p);
    const int g1 = (B + NS1 - 1) / NS1;
    k_conv1<<<g1, 256, 0, stream>>>(x, w1pb, b1, bn1s, bn1b, s_in, s_w1, s_a1, a1, B);
    const int g2 = (B + NS2 - 1) / NS2;
    k_conv2<<<g2, 256, 0, stream>>>(a1, w2p, b2, bn2s, bn2b, s_a1, s_w2, s_a2, a2, B);
    k_fc<<<(B + 15) / 16, 256, 0, stream>>>(a2, fw1p, fb1, fw2p, fb2, fw3p, fb3,
                                            s_a2, s_fw1, s_fw2, s_fw3, s_a3, s_a4,
                                            (float*)d_out, B);
}